// Round 10
// baseline (419.274 us; speedup 1.0000x reference)
//
#include <hip/hip_runtime.h>
#include <stdint.h>

#define D_IN   256
#define D_OUT  64
#define KHEADS 4
#define ROWLEN 256       // K * D_OUT elements per node row in out
#define GBM    128       // GEMM rows per block
#define LDW    264       // lWt row stride in bf16 (528 B): ds_read_b128 conflict-free
#define WBT_B  (64 * LDW * 2)   // 33792 B: transposed bf16 W, identical layout to lWt
#define CAP    128       // edges-per-row bucket capacity (Poisson(16): P(>=128) ~ 1e-60)
#define EPB    512       // edges placed per gemm block (2 rounds of 256 threads)

typedef __attribute__((ext_vector_type(8))) short bf16x8;
typedef __attribute__((ext_vector_type(4))) float f32x4;

// HW packed fp32->bf16 (RNE), S0 -> low 16, S1 -> high 16. No builtin on gfx950.
__device__ __forceinline__ unsigned cvt_pk_bf16(float lo, float hi) {
  unsigned r;
  asm("v_cvt_pk_bf16_f32 %0, %1, %2" : "=v"(r) : "v"(lo), "v"(hi));
  return r;
}

__device__ __forceinline__ bf16x8 pack8(float4 a, float4 b) {
  union { unsigned u[4]; bf16x8 v; } r;
  r.u[0] = cvt_pk_bf16(a.x, a.y);
  r.u[1] = cvt_pk_bf16(a.z, a.w);
  r.u[2] = cvt_pk_bf16(b.x, b.y);
  r.u[3] = cvt_pk_bf16(b.z, b.w);
  return r.v;
}

// ---------------------------------------------------------------------------
// prep_w: one-time W[256,64] fp32 -> WbT bf16 transposed, padded to LDW,
// byte-identical to the lWt layout every gemm block stages. 16 blocks, ~2 us.
// ---------------------------------------------------------------------------
__global__ __launch_bounds__(256) void prep_w(const float* __restrict__ W,
                                              unsigned short* __restrict__ WbT) {
  int idx = blockIdx.x * 256 + threadIdx.x;   // 0..4095
  int n  = idx >> 6;                          // 0..63  (output col)
  int k0 = (idx & 63) << 2;                   // 0..252 (k quad)
  float w0 = W[(size_t)(k0 + 0) * D_OUT + n];
  float w1 = W[(size_t)(k0 + 1) * D_OUT + n];
  float w2 = W[(size_t)(k0 + 2) * D_OUT + n];
  float w3 = W[(size_t)(k0 + 3) * D_OUT + n];
  unsigned p0 = cvt_pk_bf16(w0, w1);
  unsigned p1 = cvt_pk_bf16(w2, w3);
  *(uint2*)&WbT[(size_t)n * LDW + k0] = make_uint2(p0, p1);
}

// ---------------------------------------------------------------------------
// Fused gemm+place: every block does full gemm work; its 512-edge placement
// chunk is issued first (independent; atomic/scatter latency overlaps the
// W staging + A prefetch). Support stored HEAD-MAJOR: SqH[head][node][64]
// int8 (3.2 MB/plane fits a per-XCD L2 for the gather phase).
// C/D mapping (HW-verified): row = wave*32+rb*16+q*4+reg, col = cb*16+l16.
// Epilogue<->gather indexing cross-checked by concrete example (r=59 ->
// node 14 head 3 col 37 -> gather d16=9 byte1 -> out elem 37).
// ---------------------------------------------------------------------------
__global__ __launch_bounds__(256) void fused_gemm_place(
    const float* __restrict__ X, const unsigned short* __restrict__ WbT,
    signed char* __restrict__ SqH, float* __restrict__ scaleArr,
    const int* __restrict__ rows, const int* __restrict__ cols,
    const float* __restrict__ vals, int* __restrict__ cnt,
    uint2* __restrict__ ecv, int M, int Nnodes, int E) {
  __shared__ __align__(16) unsigned short lWt[64 * LDW];   // 33792 B
  const int t    = threadIdx.x;
  const int g    = blockIdx.x;

  // ---- inline place: this block's 512-edge chunk (independent of gemm) ----
  {
    int base = g * EPB + t;
#pragma unroll
    for (int u = 0; u < 2; ++u) {
      int e = base + u * 256;
      if (e < E) {
        int r = rows[e];
        int c = cols[e];
        float v = vals[e];
        int pos = atomicAdd(&cnt[r], 1);
        if (pos < CAP)
          ecv[((size_t)r << 7) + pos] = make_uint2((unsigned)c, __float_as_uint(v));
      }
    }
  }

  // ---- stage lWt: plain vectorized copy of precomputed WbT ----
  {
    const uint4* __restrict__ src = (const uint4*)WbT;
    uint4* dst = (uint4*)lWt;
#pragma unroll
    for (int r2 = 0; r2 < 9; ++r2) {
      int slot = t + r2 * 256;
      if (slot < WBT_B / 16) dst[slot] = src[slot];
    }
  }
  __syncthreads();

  const int wave = t >> 6;
  const int lane = t & 63;
  const int q    = lane >> 4;
  const int l16  = lane & 15;
  const long row0 = (long)g * GBM;

  long r0 = row0 + wave * 32 + l16;       if (r0 > (long)M - 1) r0 = M - 1;
  long r1 = row0 + wave * 32 + 16 + l16;  if (r1 > (long)M - 1) r1 = M - 1;
  const float* __restrict__ x0 = X + r0 * D_IN + q * 8;
  const float* __restrict__ x1 = X + r1 * D_IN + q * 8;

  f32x4 acc[2][4];
#pragma unroll
  for (int rb = 0; rb < 2; ++rb)
#pragma unroll
    for (int cb = 0; cb < 4; ++cb) acc[rb][cb] = (f32x4){0.f, 0.f, 0.f, 0.f};

  // K-loop: 8 steps of K=32; 1-step register prefetch, TLP covers the rest.
  float4 c00 = *(const float4*)(x0);
  float4 c01 = *(const float4*)(x0 + 4);
  float4 c10 = *(const float4*)(x1);
  float4 c11 = *(const float4*)(x1 + 4);
#pragma unroll
  for (int s = 0; s < 8; ++s) {
    float4 n00, n01, n10, n11;
    if (s < 7) {
      const float* p0 = x0 + (s + 1) * 32;
      const float* p1 = x1 + (s + 1) * 32;
      n00 = *(const float4*)(p0); n01 = *(const float4*)(p0 + 4);
      n10 = *(const float4*)(p1); n11 = *(const float4*)(p1 + 4);
    }
    bf16x8 a0 = pack8(c00, c01);
    bf16x8 a1 = pack8(c10, c11);
    const unsigned short* wb = &lWt[l16 * LDW + s * 32 + q * 8];
#pragma unroll
    for (int cb = 0; cb < 4; ++cb) {
      bf16x8 b = *(const bf16x8*)(wb + cb * 16 * LDW);
      acc[0][cb] = __builtin_amdgcn_mfma_f32_16x16x32_bf16(a0, b, acc[0][cb], 0, 0, 0);
      acc[1][cb] = __builtin_amdgcn_mfma_f32_16x16x32_bf16(a1, b, acc[1][cb], 0, 0, 0);
    }
    if (s < 7) { c00 = n00; c01 = n01; c10 = n10; c11 = n11; }
  }

  // ---- Epilogue: per-node max -> scale -> int8 quantize (head-major) ----
  float nm0 = 0.f, nm1 = 0.f;
#pragma unroll
  for (int cb = 0; cb < 4; ++cb)
#pragma unroll
    for (int reg = 0; reg < 4; ++reg) {
      nm0 = fmaxf(nm0, fabsf(acc[0][cb][reg]));
      nm1 = fmaxf(nm1, fabsf(acc[1][cb][reg]));
    }
#pragma unroll
  for (int d = 1; d < 16; d <<= 1) {   // butterfly within 16-lane l16 group
    nm0 = fmaxf(nm0, __shfl_xor(nm0, d, 64));
    nm1 = fmaxf(nm1, __shfl_xor(nm1, d, 64));
  }
  const float inv0 = (nm0 > 0.f) ? 127.f / nm0 : 0.f;
  const float inv1 = (nm1 > 0.f) ? 127.f / nm1 : 0.f;
  const int node_base = g * 32 + wave * 8;
  if (l16 == 0) {
    int n0 = node_base + q;
    int n1 = node_base + 4 + q;
    if (n0 < Nnodes) scaleArr[n0] = nm0 / 127.f;
    if (n1 < Nnodes) scaleArr[n1] = nm1 / 127.f;
  }
#pragma unroll
  for (int rb = 0; rb < 2; ++rb) {
    const float inv = rb ? inv1 : inv0;
#pragma unroll
    for (int cb = 0; cb < 4; ++cb)
#pragma unroll
      for (int reg = 0; reg < 4; ++reg) {
        long r = row0 + wave * 32 + rb * 16 + q * 4 + reg;
        if (r < M) {
          int qi = (int)rintf(acc[rb][cb][reg] * inv);
          int node = (int)(r >> 2);
          int head = (int)(r & 3);
          SqH[((size_t)head * Nnodes + node) * 64 + cb * 16 + l16] = (signed char)qi;
        }
      }
  }
}

// ---------------------------------------------------------------------------
// Gather-accumulate + ReLU, HEAD-SPLIT for per-XCD L2 residency.
// EXEC-UNIFORM main loop: mc/mv are zero-masked at load time for lanes >= deg,
// so the loop runs to ceil8(d0) with UNGUARDED __shfl (every shfl has full
// exec and a valid lane index <= 63; padding edges contribute v=0).
// ---------------------------------------------------------------------------
__global__ __launch_bounds__(256) void gather_kernel(
    const signed char* __restrict__ SqH, const float* __restrict__ scaleArr,
    const int* __restrict__ cnt, const uint2* __restrict__ ecv,
    float* __restrict__ out, int n, int bph) {
  const int bid  = blockIdx.x;
  const int head = bid / bph;
  const int rb   = (bid - head * bph) * 4 + (threadIdx.x >> 6);
  if (rb >= n) return;
  const int lane = threadIdx.x & 63;
  const int e2   = lane >> 4;
  const int d16  = lane & 15;
  int deg = cnt[rb];
  if (deg > CAP) deg = CAP;
  const uint2* __restrict__ bucket = ecv + ((size_t)rb << 7);

  // Whole bucket -> registers (lane i = entry i); zero-mask poisoned tail.
  unsigned long long bl = *((const unsigned long long*)bucket + lane);
  const unsigned mc = (lane < deg) ? (unsigned)bl : 0u;
  const float    mv = (lane < deg)
      ? __uint_as_float((unsigned)(bl >> 32)) * scaleArr[mc] : 0.f;

  const int* __restrict__ Sh = (const int*)SqH + (size_t)head * (size_t)n * 16;

  float4 aA = make_float4(0.f, 0.f, 0.f, 0.f);
  float4 aB = aA;
  const int d0  = deg < 64 ? deg : 64;
  const int nd0 = (d0 + 7) & ~7;           // multiple of 8, <= 64
  for (int i = 0; i < nd0; i += 8) {       // 8 edges/iter, 2 loads in flight
    const int eA = i + e2;                 // <= 59
    const int eB = i + 4 + e2;             // <= 63
    const unsigned cA = __shfl(mc, eA);    // unguarded: full-exec, valid lane
    const unsigned cB = __shfl(mc, eB);
    const float    vA = __shfl(mv, eA);    // 0 for padding edges
    const float    vB = __shfl(mv, eB);
    const int wA = Sh[(size_t)cA * 16 + d16];
    const int wB = Sh[(size_t)cB * 16 + d16];
    aA.x += vA * (float)(wA << 24 >> 24); aA.y += vA * (float)(wA << 16 >> 24);
    aA.z += vA * (float)(wA <<  8 >> 24); aA.w += vA * (float)(wA >> 24);
    aB.x += vB * (float)(wB << 24 >> 24); aB.y += vB * (float)(wB << 16 >> 24);
    aB.z += vB * (float)(wB <<  8 >> 24); aB.w += vB * (float)(wB >> 24);
  }
  if (deg > 64) {  // Poisson(16): effectively never; correctness path only.
    unsigned long long bl1 = *((const unsigned long long*)bucket + 64 + lane);
    const unsigned mc1 = (64 + lane < deg) ? (unsigned)bl1 : 0u;
    const float    mv1 = (64 + lane < deg)
        ? __uint_as_float((unsigned)(bl1 >> 32)) * scaleArr[mc1] : 0.f;
    const int ndt = (deg + 3) & ~3;        // <= 128
    for (int i = 64; i < ndt; i += 4) {
      const int idx = i + e2 - 64;         // <= 63
      const unsigned cA = __shfl(mc1, idx);
      const float    vA = __shfl(mv1, idx);
      const int wA = Sh[(size_t)cA * 16 + d16];
      aA.x += vA * (float)(wA << 24 >> 24); aA.y += vA * (float)(wA << 16 >> 24);
      aA.z += vA * (float)(wA <<  8 >> 24); aA.w += vA * (float)(wA >> 24);
    }
  }
  float4 a;
  a.x = aA.x + aB.x; a.y = aA.y + aB.y; a.z = aA.z + aB.z; a.w = aA.w + aB.w;
  // reduce across the 4 e2 groups (butterfly over lane bits 4,5)
  a.x += __shfl_xor(a.x, 16, 64); a.y += __shfl_xor(a.y, 16, 64);
  a.z += __shfl_xor(a.z, 16, 64); a.w += __shfl_xor(a.w, 16, 64);
  a.x += __shfl_xor(a.x, 32, 64); a.y += __shfl_xor(a.y, 32, 64);
  a.z += __shfl_xor(a.z, 32, 64); a.w += __shfl_xor(a.w, 32, 64);
  if (e2 == 0) {
    f32x4 res;
    res[0] = fmaxf(a.x, 0.f);
    res[1] = fmaxf(a.y, 0.f);
    res[2] = fmaxf(a.z, 0.f);
    res[3] = fmaxf(a.w, 0.f);
    __builtin_nontemporal_store(
        res, (f32x4*)&out[(size_t)rb * ROWLEN + head * 64 + (d16 << 2)]);
  }
}

// ---------------------------------------------------------------------------
extern "C" void kernel_launch(void* const* d_in, const int* in_sizes, int n_in,
                              void* d_out, int out_size, void* d_ws, size_t ws_size,
                              hipStream_t stream) {
  const float* x    = (const float*)d_in[0];
  const float* w    = (const float*)d_in[1];
  const int*   rows = (const int*)d_in[2];
  const int*   cols = (const int*)d_in[3];
  const float* vals = (const float*)d_in[4];
  float* out = (float*)d_out;

  const int E = in_sizes[2];
  const int N = in_sizes[0] / (KHEADS * D_IN);   // 50000 nodes
  const int M = N * KHEADS;                      // 200000 GEMM rows

  char* ws = (char*)d_ws;
  size_t o = 0;
  signed char* SqH = (signed char*)(ws + o); o += (size_t)M * D_OUT;  // 12.8 MB
  o = (o + 15) & ~(size_t)15;
  float* scaleArr = (float*)(ws + o); o += (size_t)N * sizeof(float); // 200 KB
  o = (o + 15) & ~(size_t)15;
  int* cnt = (int*)(ws + o); o += (size_t)N * sizeof(int);            // 200 KB
  o = (o + 63) & ~(size_t)63;
  unsigned short* WbT = (unsigned short*)(ws + o); o += WBT_B;        // 33 KB
  o = (o + 15) & ~(size_t)15;
  uint2* ecv = (uint2*)(ws + o);                                      // 51.2 MB

  hipMemsetAsync(cnt, 0, (size_t)N * sizeof(int), stream);

  int G = (M + GBM - 1) / GBM;                   // 1563
  const int Ge = (E + EPB - 1) / EPB;            // 1563 (coverage for edges)
  if (Ge > G) G = Ge;
  prep_w<<<16, 256, 0, stream>>>(w, WbT);
  fused_gemm_place<<<G, 256, 0, stream>>>(x, WbT, SqH, scaleArr, rows, cols,
                                          vals, cnt, ecv, M, N, E);
  const int bph = (N + 3) / 4;                   // blocks per head pass
  gather_kernel<<<bph * KHEADS, 256, 0, stream>>>(SqH, scaleArr, cnt, ecv,
                                                  out, N, bph);
}